// Round 1
// baseline (216.018 us; speedup 1.0000x reference)
//
#include <hip/hip_runtime.h>

#define B_ 8
#define S_ 4096
#define D_ 64

// ---------------------------------------------------------------------------
// Kernel 1: per (batch, seq-chunk) block computes a partial M = K_r^T V_r
// (64x64) over its chunk of the sequence, RoPE applied on the fly.
// Partial tiles land in d_ws at part[b*nchunk + chunk][64*64].
// ---------------------------------------------------------------------------
__global__ __launch_bounds__(256) void rope_ktv_partials(
    const float* __restrict__ K, const float* __restrict__ V,
    const float* __restrict__ FK, const float* __restrict__ FV,
    float* __restrict__ part, int nchunk, int rowsPerChunk)
{
    __shared__ float kbuf[16][64];
    __shared__ float vbuf[16][64];
    const int t  = threadIdx.x;
    const int b  = blockIdx.x / nchunk;
    const int sBase = (blockIdx.x - b * nchunk) * rowsPerChunk;

    const int sl = t >> 4;          // staging row 0..15
    const int e0 = (t & 15) << 2;   // staging elem 0,4,...,60
    const int i0 = (t >> 4) << 2;   // acc tile row base (k index)
    const int j0 = (t & 15) << 2;   // acc tile col base (v index)

    const float* kb = K + (size_t)b * S_ * D_;
    const float* vb = V + (size_t)b * S_ * D_;

    float acc[4][4];
    #pragma unroll
    for (int a = 0; a < 4; ++a)
        #pragma unroll
        for (int c = 0; c < 4; ++c) acc[a][c] = 0.f;

    for (int s0 = sBase; s0 < sBase + rowsPerChunk; s0 += 16) {
        const int s = s0 + sl;
        // 16B/lane loads; RoPE pairs (2p,2p+1) live inside the float4.
        float4 k4 = *(const float4*)(kb + (size_t)s * D_ + e0);
        float4 v4 = *(const float4*)(vb + (size_t)s * D_ + e0);
        float4 fk = *(const float4*)(FK + (size_t)s * D_ + e0); // (c0,s0,c1,s1)
        float4 fv = *(const float4*)(FV + (size_t)s * D_ + e0);
        float4 kr, vr;
        kr.x = k4.x*fk.x - k4.y*fk.y;  kr.y = k4.x*fk.y + k4.y*fk.x;
        kr.z = k4.z*fk.z - k4.w*fk.w;  kr.w = k4.z*fk.w + k4.w*fk.z;
        vr.x = v4.x*fv.x - v4.y*fv.y;  vr.y = v4.x*fv.y + v4.y*fv.x;
        vr.z = v4.z*fv.z - v4.w*fv.w;  vr.w = v4.z*fv.w + v4.w*fv.z;
        __syncthreads();
        *(float4*)&kbuf[sl][e0] = kr;
        *(float4*)&vbuf[sl][e0] = vr;
        __syncthreads();
        #pragma unroll
        for (int r = 0; r < 16; ++r) {
            float4 ka = *(const float4*)&kbuf[r][i0];  // broadcast (4 addrs/wave)
            float4 vv = *(const float4*)&vbuf[r][j0];  // 2-way bank alias = free
            acc[0][0] += ka.x*vv.x; acc[0][1] += ka.x*vv.y; acc[0][2] += ka.x*vv.z; acc[0][3] += ka.x*vv.w;
            acc[1][0] += ka.y*vv.x; acc[1][1] += ka.y*vv.y; acc[1][2] += ka.y*vv.z; acc[1][3] += ka.y*vv.w;
            acc[2][0] += ka.z*vv.x; acc[2][1] += ka.z*vv.y; acc[2][2] += ka.z*vv.z; acc[2][3] += ka.z*vv.w;
            acc[3][0] += ka.w*vv.x; acc[3][1] += ka.w*vv.y; acc[3][2] += ka.w*vv.z; acc[3][3] += ka.w*vv.w;
        }
    }
    float* p = part + (size_t)blockIdx.x * (D_ * D_);
    #pragma unroll
    for (int a = 0; a < 4; ++a)
        *(float4*)(p + (size_t)(i0 + a) * D_ + j0) =
            make_float4(acc[a][0], acc[a][1], acc[a][2], acc[a][3]);
}

// ---------------------------------------------------------------------------
// Kernel 2: per (batch, row-block) block: reduce partials -> Mt (transposed,
// stride-65 padded LDS), then O[row][j] = scale * sum_i q_r[row][i]*M[i][j].
// ---------------------------------------------------------------------------
__global__ __launch_bounds__(256) void rope_q_matmul(
    const float* __restrict__ Q, const float* __restrict__ FQ,
    const float* __restrict__ part, float* __restrict__ OUT,
    int nchunk, int nb2, int rowsPerBlock)
{
    __shared__ float Mt[64][65];     // Mt[j][i] = M[i][j]; 65 => banks (j+i)%32
    __shared__ float qbuf[16][64];
    const int t = threadIdx.x;
    const int b = blockIdx.x / nb2;
    const int rowBase = (blockIdx.x - b * nb2) * rowsPerBlock;

    // Reduce nchunk partial tiles into Mt. Coalesced global reads.
    #pragma unroll
    for (int c = 0; c < 16; ++c) {
        const int cell = t + (c << 8);           // cell = i*64 + j
        float ssum = 0.f;
        for (int p = 0; p < nchunk; ++p)
            ssum += part[((size_t)(b * nchunk + p)) * (D_ * D_) + cell];
        Mt[cell & 63][cell >> 6] = ssum;
    }
    __syncthreads();

    const int sl = t >> 4;
    const int e0 = (t & 15) << 2;
    const int j  = t & 63;            // output column
    const int rg = (t >> 6) << 2;     // local row group base (0,4,8,12)
    const float* qb = Q + (size_t)b * S_ * D_;

    for (int it = 0; it < rowsPerBlock / 16; ++it) {
        const int row = rowBase + (it << 4) + sl;
        float4 q4 = *(const float4*)(qb + (size_t)row * D_ + e0);
        float4 f4 = *(const float4*)(FQ + (size_t)row * D_ + e0);
        float4 qr;
        qr.x = q4.x*f4.x - q4.y*f4.y;  qr.y = q4.x*f4.y + q4.y*f4.x;
        qr.z = q4.z*f4.z - q4.w*f4.w;  qr.w = q4.z*f4.w + q4.w*f4.z;
        __syncthreads();                 // protect prev iter's qbuf readers
        *(float4*)&qbuf[sl][e0] = qr;
        __syncthreads();

        float a0 = 0.f, a1 = 0.f, a2 = 0.f, a3 = 0.f;
        const float* mrow = &Mt[j][0];
        #pragma unroll
        for (int i = 0; i < 64; i += 4) {
            const float m0 = mrow[i], m1 = mrow[i+1], m2 = mrow[i+2], m3 = mrow[i+3];
            float4 qa = *(const float4*)&qbuf[rg + 0][i];  // broadcast reads
            float4 qc = *(const float4*)&qbuf[rg + 1][i];
            float4 qd = *(const float4*)&qbuf[rg + 2][i];
            float4 qe = *(const float4*)&qbuf[rg + 3][i];
            a0 += qa.x*m0 + qa.y*m1 + qa.z*m2 + qa.w*m3;
            a1 += qc.x*m0 + qc.y*m1 + qc.z*m2 + qc.w*m3;
            a2 += qd.x*m0 + qd.y*m1 + qd.z*m2 + qd.w*m3;
            a3 += qe.x*m0 + qe.y*m1 + qe.z*m2 + qe.w*m3;
        }
        float* ob = OUT + ((size_t)b * S_ + rowBase + (it << 4) + rg) * D_ + j;
        const float sc = 0.125f;   // 1/sqrt(64)
        ob[0]      = sc * a0;      // coalesced: lane j -> column j
        ob[D_]     = sc * a1;
        ob[2 * D_] = sc * a2;
        ob[3 * D_] = sc * a3;
    }
}

extern "C" void kernel_launch(void* const* d_in, const int* in_sizes, int n_in,
                              void* d_out, int out_size, void* d_ws, size_t ws_size,
                              hipStream_t stream)
{
    const float* Q  = (const float*)d_in[0];
    const float* K  = (const float*)d_in[1];
    const float* V  = (const float*)d_in[2];
    const float* FQ = (const float*)d_in[3];
    const float* FK = (const float*)d_in[4];
    const float* FV = (const float*)d_in[5];
    float* OUT  = (float*)d_out;
    float* part = (float*)d_ws;

    // 32 seq-chunks per batch -> 4 MB of partials; shrink if ws is smaller.
    int nchunk = 32;
    while (nchunk > 1 &&
           (size_t)B_ * nchunk * (D_ * D_) * sizeof(float) > ws_size)
        nchunk >>= 1;
    const int rowsPerChunk = S_ / nchunk;

    rope_ktv_partials<<<dim3(B_ * nchunk), dim3(256), 0, stream>>>(
        K, V, FK, FV, part, nchunk, rowsPerChunk);

    const int nb2 = 32;                    // row-blocks per batch
    const int rowsPerBlock = S_ / nb2;     // 128
    rope_q_matmul<<<dim3(B_ * nb2), dim3(256), 0, stream>>>(
        Q, FQ, part, OUT, nchunk, nb2, rowsPerBlock);
}

// Round 2
// 95.146 us; speedup vs baseline: 2.2704x; 2.2704x over previous
//
#include <hip/hip_runtime.h>

#define B_ 8
#define S_ 4096
#define D_ 64

// ---------------------------------------------------------------------------
// Kernel 1: per (batch, seq-chunk) block computes a partial M = K_r^T V_r
// (64x64) over its chunk, RoPE on the fly. 32-row LDS stages, software-
// pipelined global prefetch so the pre-barrier vmcnt(0) drain overlaps the
// 512-FMA compute loop instead of exposing ~900cy HBM latency per stage.
// ---------------------------------------------------------------------------
__global__ __launch_bounds__(256) void rope_ktv_partials(
    const float* __restrict__ K, const float* __restrict__ V,
    const float* __restrict__ FK, const float* __restrict__ FV,
    float* __restrict__ part, int nchunk, int rowsPerChunk)
{
    __shared__ float kbuf[32][64];
    __shared__ float vbuf[32][64];
    const int t  = threadIdx.x;
    const int b  = blockIdx.x / nchunk;
    const int sBase = (blockIdx.x - b * nchunk) * rowsPerChunk;

    const int sl = t >> 4;          // staging row 0..15 (and +16)
    const int e0 = (t & 15) << 2;   // elem 0,4,...,60
    const int i0 = (t >> 4) << 2;   // acc tile row base (k index)
    const int j0 = (t & 15) << 2;   // acc tile col base (v index)

    const float* kb = K + (size_t)b * S_ * D_;
    const float* vb = V + (size_t)b * S_ * D_;

    float acc[4][4];
    #pragma unroll
    for (int a = 0; a < 4; ++a)
        #pragma unroll
        for (int c = 0; c < 4; ++c) acc[a][c] = 0.f;

    const int nStages = rowsPerChunk >> 5;   // 32 rows per stage

    // prefetch stage 0 (2 rows per thread)
    int s = sBase + sl;
    float4 kA = *(const float4*)(kb + (size_t)s * D_ + e0);
    float4 vA = *(const float4*)(vb + (size_t)s * D_ + e0);
    float4 fA = *(const float4*)(FK + (size_t)s * D_ + e0);
    float4 gA = *(const float4*)(FV + (size_t)s * D_ + e0);
    float4 kB = *(const float4*)(kb + (size_t)(s + 16) * D_ + e0);
    float4 vB = *(const float4*)(vb + (size_t)(s + 16) * D_ + e0);
    float4 fB = *(const float4*)(FK + (size_t)(s + 16) * D_ + e0);
    float4 gB = *(const float4*)(FV + (size_t)(s + 16) * D_ + e0);

    for (int it = 0; it < nStages; ++it) {
        float4 kr, vr;
        // RoPE current stage registers
        kr.x = kA.x*fA.x - kA.y*fA.y;  kr.y = kA.x*fA.y + kA.y*fA.x;
        kr.z = kA.z*fA.z - kA.w*fA.w;  kr.w = kA.z*fA.w + kA.w*fA.z;
        vr.x = vA.x*gA.x - vA.y*gA.y;  vr.y = vA.x*gA.y + vA.y*gA.x;
        vr.z = vA.z*gA.z - vA.w*gA.w;  vr.w = vA.z*gA.w + vA.w*gA.z;
        float4 kr2, vr2;
        kr2.x = kB.x*fB.x - kB.y*fB.y; kr2.y = kB.x*fB.y + kB.y*fB.x;
        kr2.z = kB.z*fB.z - kB.w*fB.w; kr2.w = kB.z*fB.w + kB.w*fB.z;
        vr2.x = vB.x*gB.x - vB.y*gB.y; vr2.y = vB.x*gB.y + vB.y*gB.x;
        vr2.z = vB.z*gB.z - vB.w*gB.w; vr2.w = vB.z*gB.w + vB.w*gB.z;

        __syncthreads();                         // prev stage readers done
        *(float4*)&kbuf[sl][e0]      = kr;
        *(float4*)&vbuf[sl][e0]      = vr;
        *(float4*)&kbuf[sl + 16][e0] = kr2;
        *(float4*)&vbuf[sl + 16][e0] = vr2;
        __syncthreads();

        // issue next stage's loads now; latency hides under the r-loop
        if (it + 1 < nStages) {
            s = sBase + ((it + 1) << 5) + sl;
            kA = *(const float4*)(kb + (size_t)s * D_ + e0);
            vA = *(const float4*)(vb + (size_t)s * D_ + e0);
            fA = *(const float4*)(FK + (size_t)s * D_ + e0);
            gA = *(const float4*)(FV + (size_t)s * D_ + e0);
            kB = *(const float4*)(kb + (size_t)(s + 16) * D_ + e0);
            vB = *(const float4*)(vb + (size_t)(s + 16) * D_ + e0);
            fB = *(const float4*)(FK + (size_t)(s + 16) * D_ + e0);
            gB = *(const float4*)(FV + (size_t)(s + 16) * D_ + e0);
        }

        #pragma unroll
        for (int r = 0; r < 32; ++r) {
            float4 ka = *(const float4*)&kbuf[r][i0];  // 4 addrs/wave
            float4 vv = *(const float4*)&vbuf[r][j0];  // 16 addrs/wave
            acc[0][0] += ka.x*vv.x; acc[0][1] += ka.x*vv.y; acc[0][2] += ka.x*vv.z; acc[0][3] += ka.x*vv.w;
            acc[1][0] += ka.y*vv.x; acc[1][1] += ka.y*vv.y; acc[1][2] += ka.y*vv.z; acc[1][3] += ka.y*vv.w;
            acc[2][0] += ka.z*vv.x; acc[2][1] += ka.z*vv.y; acc[2][2] += ka.z*vv.z; acc[2][3] += ka.z*vv.w;
            acc[3][0] += ka.w*vv.x; acc[3][1] += ka.w*vv.y; acc[3][2] += ka.w*vv.z; acc[3][3] += ka.w*vv.w;
        }
    }

    float* p = part + (size_t)blockIdx.x * (D_ * D_);
    #pragma unroll
    for (int a = 0; a < 4; ++a)
        *(float4*)(p + (size_t)(i0 + a) * D_ + j0) =
            make_float4(acc[a][0], acc[a][1], acc[a][2], acc[a][3]);
}

// ---------------------------------------------------------------------------
// Kernel 1.5: reduce partials -> M[8][64*64]. One thread per (b, cell);
// nchunk independent fully-unrolled coalesced loads -> one vmcnt drain.
// ---------------------------------------------------------------------------
__global__ __launch_bounds__(256) void reduce_partials(
    const float* __restrict__ part, float* __restrict__ M, int nchunk)
{
    const int g    = blockIdx.x * 256 + threadIdx.x;   // 0..32767
    const int b    = g >> 12;
    const int cell = g & 4095;
    const float* p = part + ((size_t)b * nchunk) * (D_ * D_) + cell;
    float ssum = 0.f;
    if (nchunk == 32) {
        #pragma unroll
        for (int i = 0; i < 32; ++i) ssum += p[(size_t)i * (D_ * D_)];
    } else {
        #pragma unroll 8
        for (int i = 0; i < nchunk; ++i) ssum += p[(size_t)i * (D_ * D_)];
    }
    M[g] = ssum;
}

// ---------------------------------------------------------------------------
// Kernel 2: per (batch, 32-row block): load M (16KB, 4 parallel float4/thr)
// into Mt[j][i] (stride-65 -> conflict-free column reads), RoPE+stage 32 q
// rows, each thread computes 8 rows x 1 col. q reads are wave-uniform b128
// broadcasts; Mt reads are 64-lane stride-65 scalars (conflict-free).
// ---------------------------------------------------------------------------
__global__ __launch_bounds__(256) void rope_q_matmul(
    const float* __restrict__ Q, const float* __restrict__ FQ,
    const float* __restrict__ M, float* __restrict__ OUT, int nb2)
{
    __shared__ float Mt[64][65];
    __shared__ float qbuf[32][64];
    const int t = threadIdx.x;
    const int b = blockIdx.x / nb2;
    const int rowBase = (blockIdx.x - b * nb2) * 32;

    const int sl = t >> 4;
    const int e0 = (t & 15) << 2;
    const float* qb = Q + (size_t)b * S_ * D_;

    // issue q + freq loads (2 rows/thread)
    const int r1 = rowBase + sl;
    float4 qA = *(const float4*)(qb + (size_t)r1 * D_ + e0);
    float4 fA = *(const float4*)(FQ + (size_t)r1 * D_ + e0);
    float4 qB = *(const float4*)(qb + (size_t)(r1 + 16) * D_ + e0);
    float4 fB = *(const float4*)(FQ + (size_t)(r1 + 16) * D_ + e0);

    // issue M loads: 4 independent float4 per thread
    const float* mb = M + (size_t)b * (D_ * D_);
    float4 m0 = *(const float4*)(mb + (t << 2));
    float4 m1 = *(const float4*)(mb + 1024 + (t << 2));
    float4 m2 = *(const float4*)(mb + 2048 + (t << 2));
    float4 m3 = *(const float4*)(mb + 3072 + (t << 2));

    // RoPE q, stage to LDS
    float4 qr, qr2;
    qr.x  = qA.x*fA.x - qA.y*fA.y;  qr.y  = qA.x*fA.y + qA.y*fA.x;
    qr.z  = qA.z*fA.z - qA.w*fA.w;  qr.w  = qA.z*fA.w + qA.w*fA.z;
    qr2.x = qB.x*fB.x - qB.y*fB.y;  qr2.y = qB.x*fB.y + qB.y*fB.x;
    qr2.z = qB.z*fB.z - qB.w*fB.w;  qr2.w = qB.z*fB.w + qB.w*fB.z;
    *(float4*)&qbuf[sl][e0]      = qr;
    *(float4*)&qbuf[sl + 16][e0] = qr2;

    // scatter M transposed: cell = c*1024 + t*4 + d ; Mt[cell&63][cell>>6]
    {
        const int c0 = (t << 2);
        const float mv[16] = { m0.x, m0.y, m0.z, m0.w,  m1.x, m1.y, m1.z, m1.w,
                               m2.x, m2.y, m2.z, m2.w,  m3.x, m3.y, m3.z, m3.w };
        #pragma unroll
        for (int c = 0; c < 4; ++c)
            #pragma unroll
            for (int d = 0; d < 4; ++d) {
                const int cell = c * 1024 + c0 + d;
                Mt[cell & 63][cell >> 6] = mv[c * 4 + d];
            }
    }
    __syncthreads();

    const int j  = t & 63;            // output column (lane)
    const int rg = (t >> 6) << 3;     // wave-uniform row group: 0,8,16,24
    float a[8];
    #pragma unroll
    for (int r = 0; r < 8; ++r) a[r] = 0.f;

    #pragma unroll
    for (int i = 0; i < 64; i += 4) {
        const float w0 = Mt[j][i], w1 = Mt[j][i+1], w2 = Mt[j][i+2], w3 = Mt[j][i+3];
        #pragma unroll
        for (int r = 0; r < 8; ++r) {
            float4 q = *(const float4*)&qbuf[rg + r][i];   // broadcast
            a[r] += q.x*w0 + q.y*w1 + q.z*w2 + q.w*w3;
        }
    }

    float* ob = OUT + ((size_t)b * S_ + rowBase + rg) * D_ + j;
    const float sc = 0.125f;   // 1/sqrt(64)
    #pragma unroll
    for (int r = 0; r < 8; ++r)
        ob[(size_t)r * D_] = sc * a[r];
}

extern "C" void kernel_launch(void* const* d_in, const int* in_sizes, int n_in,
                              void* d_out, int out_size, void* d_ws, size_t ws_size,
                              hipStream_t stream)
{
    const float* Q  = (const float*)d_in[0];
    const float* K  = (const float*)d_in[1];
    const float* V  = (const float*)d_in[2];
    const float* FQ = (const float*)d_in[3];
    const float* FK = (const float*)d_in[4];
    const float* FV = (const float*)d_in[5];
    float* OUT = (float*)d_out;

    float* M    = (float*)d_ws;                       // 8*4096 floats = 128 KB
    float* part = (float*)d_ws + (size_t)B_ * D_ * D_;

    int nchunk = 32;
    while (nchunk > 1 &&
           (size_t)(B_ * D_ * D_ + B_ * nchunk * D_ * D_) * sizeof(float) > ws_size)
        nchunk >>= 1;
    const int rowsPerChunk = S_ / nchunk;

    rope_ktv_partials<<<dim3(B_ * nchunk), dim3(256), 0, stream>>>(
        K, V, FK, FV, part, nchunk, rowsPerChunk);

    reduce_partials<<<dim3((B_ * D_ * D_) / 256), dim3(256), 0, stream>>>(
        part, M, nchunk);

    const int nb2 = S_ / 32;   // 128 row-blocks per batch -> 1024 blocks
    rope_q_matmul<<<dim3(B_ * nb2), dim3(256), 0, stream>>>(
        Q, FQ, M, OUT, nb2);
}